// Round 15
// baseline (69.779 us; speedup 1.0000x reference)
//
#include <hip/hip_runtime.h>

// ConvTranspose3d(3->16,k=3,s=2,p=1) + per-channel BN-norm + 2x avgpool2, fully fused.
// Identity 1: pooled output = stride-2 3^3 conv of x with collapsed kernel G (+norm inline).
// Identity 2: sum(y), sum(y^2) via x-autocorrelation at 27 lags + inclusion-exclusion
// boundary corrections (faces/edges/corners).
// R15: 2-plane slabs (1024 autocorr blocks, 36.5KB LDS -> 4 blocks/CU), 4-lane DPP
// pre-reduce before rbuf (4x smaller reduction), conflict-fixed stage1. 4 launches.

#define I3 32768
#define NS 98304              // n stride in x = 3*32768
#define COUNT_Y 8001504.0f    // 32*63^3
#define POOL3 3375
#define TOTAL_OUT 1728000

// ws layout (floats)
#define WS_G    0        // 1296
#define WS_A3P  1296     // 1024*162 = 165888
#define WS_X3P  167184   // 1024*3   = 3072
#define WS_A2P  170256   // 486*32   = 15552
#define WS_X2P  185808   // 18*32    = 576
#define WS_A1   186384   // 324
#define WS_X1   186708   // 36
#define WS_A3R  186744   // 246
#define WS_AB   186990   // 32  -> 187022 floats ~ 748 KB

// mega smem layout (floats)
#define SM_XS   0        // [3][4][34][16] = 6528
#define SM_HLO  6528     // [3][4][34] = 408
#define SM_HHI  6936     // 408
#define SM_RBUF 7344     // 64*20 = 1280
#define SM_RB2  8624     // 16*20 = 320
#define SM_REDA 8944     // 9*20  = 180
#define SM_REDX 9124     // 12
#define SM_TOT  9136     // 36,544 B -> 4 blocks/CU

__device__ __forceinline__ float4 add4(float4 a, float4 b) {
    return make_float4(a.x + b.x, a.y + b.y, a.z + b.z, a.w + b.w);
}

// ---------- mega: faces(192) + edges(12) + prep_G(6) + autocorr(1024) ----------
__global__ __launch_bounds__(256, 4) void mega_k(
    const float* __restrict__ x, const float* __restrict__ w,
    float* __restrict__ A3p, float* __restrict__ X3p,
    float* __restrict__ A2P, float* __restrict__ X2P,
    float* __restrict__ A1, float* __restrict__ X1,
    float* __restrict__ G)
{
    const int b = blockIdx.x;
    const int tid = threadIdx.x;
    __shared__ float smem[SM_TOT];

    #define PL(ci,u,v) smem[((ci)*32+(u))*33+(v)]
    if (b < 192) {
        // ======== faces ========
        const int f = b >> 5, n = b & 31;
        const int s = f >> 1, e = (f & 1) ? 31 : 0;
        int su, sv, off;
        if (s == 0)      { su = 32;   sv = 1;  off = e * 1024; }
        else if (s == 1) { su = 1024; sv = 1;  off = e * 32;   }
        else             { su = 1024; sv = 32; off = e;        }
        const float* xb = x + (size_t)n * NS + off;
        for (int idx = tid; idx < 3072; idx += 256) {
            const int ci = idx >> 10, r = idx & 1023, u = r >> 5, v = r & 31;
            PL(ci, u, v) = xb[ci * I3 + u * su + v * sv];
        }
        __syncthreads();
        const int grp = tid >> 5, u = tid & 31;
        #pragma unroll 1
        for (int j = grp; j < 84; j += 8) {
            float t2 = 0.f;
            if (j < 81) {
                const int p = j / 9, lag = j % 9;
                const int du = lag / 3 - 1, dv = lag % 3 - 1;
                const int ci = p / 3, cj = p % 3;
                const int un = u + du;
                if ((unsigned)un < 32u) {
                    const int vlo = (dv == -1) ? 1 : 0, vhi = (dv == 1) ? 30 : 31;
                    const float* ro = &PL(ci, u, 0);
                    const float* rn = &PL(cj, un, dv);
                    for (int v = vlo; v <= vhi; ++v) t2 = fmaf(ro[v], rn[v], t2);
                }
            } else {
                const int ci = j - 81;
                for (int v = 0; v < 32; ++v) t2 += PL(ci, u, v);
            }
            #pragma unroll
            for (int m = 1; m < 32; m <<= 1) t2 += __shfl_xor(t2, m, 32);
            if (u == 0) {
                if (j < 81) A2P[(f * 81 + j) * 32 + n] = t2;
                else        X2P[(f * 3 + (j - 81)) * 32 + n] = t2;
            }
        }
        return;
    }

    if (b < 204) {
        // ======== edges ========
        const int e12 = b - 192;
        const int dp = e12 >> 2;
        const int e1 = ((e12 >> 1) & 1) ? 31 : 0, e2 = (e12 & 1) ? 31 : 0;
        int st, off;
        if (dp == 0)      { st = 1;    off = e1 * 1024 + e2 * 32; }
        else if (dp == 1) { st = 32;   off = e1 * 1024 + e2;      }
        else              { st = 1024; off = e1 * 32 + e2;        }
        for (int idx = tid; idx < 3072; idx += 256) {
            const int ci = idx >> 10, r = idx & 1023, n = r >> 5, v = r & 31;
            PL(ci, n, v) = x[(size_t)n * NS + ci * I3 + off + v * st];
        }
        __syncthreads();
        const int grp = tid >> 5, n2 = tid & 31;
        #pragma unroll 1
        for (int j = grp; j < 30; j += 8) {
            float t = 0.f;
            if (j < 27) {
                const int p = j / 3, dt = j % 3 - 1;
                const int ci = p / 3, cj = p % 3;
                const int vlo = (dt == -1) ? 1 : 0, vhi = (dt == 1) ? 30 : 31;
                const float* ro = &PL(ci, n2, 0);
                const float* rn = &PL(cj, n2, dt);
                for (int v = vlo; v <= vhi; ++v) t = fmaf(ro[v], rn[v], t);
            } else {
                const int ci = j - 27;
                for (int v = 0; v < 32; ++v) t += PL(ci, n2, v);
            }
            #pragma unroll
            for (int m = 1; m < 32; m <<= 1) t += __shfl_xor(t, m, 32);
            if (n2 == 0) {
                if (j < 27) A1[e12 * 27 + j] = t;
                else        X1[e12 * 3 + (j - 27)] = t;
            }
        }
        return;
    }

    if (b < 210) {
        // ======== prep_G ========
        const int idx = (b - 204) * 256 + tid;
        if (idx >= 1296) return;
        const int ci = idx / 432, rem = idx % 432, co = rem / 27, j = rem % 27;
        const int jd = j / 9, jh = (j / 3) % 3, jw = j % 3;
        const int SLEN[3] = {2, 3, 1};
        const int SK[3][3] = {{1, 2, 0}, {0, 1, 2}, {0, 0, 0}};
        const float* wp = w + (ci * 16 + co) * 27;
        float s = 0.f;
        for (int a = 0; a < SLEN[jd]; ++a)
            for (int bq = 0; bq < SLEN[jh]; ++bq)
                for (int c = 0; c < SLEN[jw]; ++c)
                    s += wp[SK[jd][a] * 9 + SK[jh][bq] * 3 + SK[jw][c]];
        G[idx] = s;
        return;
    }

    // ======== 3D autocorrelation: 2-plane slab, symmetric pairs ========
    {
        const int ab_ = b - 210;            // 0..1023
        const int bx = ab_ >> 5, n = ab_ & 31;
        const int dblk = bx >> 1, whalf = bx & 1;
        const int d0 = dblk * 2, w0 = whalf * 16;
        const int dth = tid >> 7;           // 0..1: own d-plane
        const int h   = (tid >> 2) & 31;
        const int w4  = tid & 3;
        const int wave = tid >> 6, lane = tid & 63;
        const int dp_own = 1 + dth;

        #define XS(cp,hh,ww)  smem[SM_XS + ((cp)*34+(hh))*16+(ww)]   // cp = ci*4+dp

        // zero-init: XS rows 0/33 (384) + halo rows 0/33 (48)
        for (int i = tid; i < 384; i += 256) {
            const int cp = i >> 5, r = i & 31;
            const int row = (r < 16) ? 0 : 33, ww = r & 15;
            smem[SM_XS + (cp * 34 + row) * 16 + ww] = 0.f;
        }
        if (tid < 48) {
            const int arr = tid / 24, r = tid % 24, cp = r >> 1;
            const int row = (r & 1) ? 33 : 0;
            smem[SM_HLO + arr * 408 + cp * 34 + row] = 0.f;
        }

        // register-staged main load: 6 float4 per thread
        float4 st[6];
        #pragma unroll
        for (int k = 0; k < 6; ++k) {
            const int i = tid + k * 256;
            const int c4 = i & 3, hh = (i >> 2) & 31, cp = i >> 7;  // cp = ci*4+dp
            const int dp = cp & 3, ci = cp >> 2;
            const int d = d0 - 1 + dp;
            const bool v = ((unsigned)d < 32u);
            const int dc = v ? d : 0;
            const float4 f = *reinterpret_cast<const float4*>(
                x + (size_t)n * NS + ci * I3 + dc * 1024 + hh * 32 + w0 + c4 * 4);
            st[k] = v ? f : make_float4(0.f, 0.f, 0.f, 0.f);
        }
        // register-staged halo load: 3 scalars per thread
        float hv[3];
        #pragma unroll
        for (int k = 0; k < 3; ++k) {
            const int i = tid + k * 256;                 // < 768
            const int side = i & 1, hh = (i >> 1) & 31, cp = i >> 6;
            const int dp = cp & 3, ci = cp >> 2;
            const int d = d0 - 1 + dp;
            const int gw = side ? (w0 + 16) : (w0 - 1);
            const bool v = ((unsigned)d < 32u) && ((unsigned)gw < 32u);
            const int dc = ((unsigned)d < 32u) ? d : 0;
            const int gwc = min(max(gw, 0), 31);
            const float f = x[(size_t)n * NS + ci * I3 + dc * 1024 + hh * 32 + gwc];
            hv[k] = v ? f : 0.f;
        }
        #pragma unroll
        for (int k = 0; k < 6; ++k) {
            const int i = tid + k * 256;
            const int c4 = i & 3, hh = (i >> 2) & 31, cp = i >> 7;
            *reinterpret_cast<float4*>(&XS(cp, hh + 1, c4 * 4)) = st[k];
        }
        #pragma unroll
        for (int k = 0; k < 3; ++k) {
            const int i = tid + k * 256;
            const int side = i & 1, hh = (i >> 1) & 31, cp = i >> 6;
            if (side) smem[SM_HHI + cp * 34 + hh + 1] = hv[k];
            else      smem[SM_HLO + cp * 34 + hh + 1] = hv[k];
        }
        __syncthreads();

        // hoisted own-plane loads + X sums
        float4 ov[3];
        #pragma unroll
        for (int ci = 0; ci < 3; ++ci)
            ov[ci] = *reinterpret_cast<const float4*>(&XS(ci * 4 + dp_own, h + 1, w4 * 4));
        float sx[3];
        #pragma unroll
        for (int ci = 0; ci < 3; ++ci)
            sx[ci] = ov[ci].x + ov[ci].y + ov[ci].z + ov[ci].w;
        #pragma unroll
        for (int m = 1; m < 64; m <<= 1) {
            sx[0] += __shfl_xor(sx[0], m, 64);
            sx[1] += __shfl_xor(sx[1], m, 64);
            sx[2] += __shfl_xor(sx[2], m, 64);
        }
        if (lane == 0) {
            smem[SM_REDX + wave * 3 + 0] = sx[0];
            smem[SM_REDX + wave * 3 + 1] = sx[1];
            smem[SM_REDX + wave * 3 + 2] = sx[2];
        }

        #pragma unroll 1
        for (int ddh = 0; ddh < 9; ++ddh) {
            const int dd = ddh / 3 - 1, dh = ddh % 3 - 1;
            const int dpn = dp_own + dd, hn = h + 1 + dh;
            float acc[18];
            #pragma unroll
            for (int j = 0; j < 18; ++j) acc[j] = 0.f;

            #pragma unroll
            for (int cj = 0; cj < 3; ++cj) {
                const int cp2 = cj * 4 + dpn;
                const float4 bv = *reinterpret_cast<const float4*>(&XS(cp2, hn, w4 * 4));
                float nxt = __shfl(bv.x, lane + 1, 64);
                float prv = __shfl(bv.w, lane - 1, 64);
                if (w4 == 3) nxt = smem[SM_HHI + cp2 * 34 + hn];
                if (w4 == 0) prv = smem[SM_HLO + cp2 * 34 + hn];
                #pragma unroll
                for (int ci = 0; ci <= cj; ++ci) {
                    const int q = (cj == 0) ? 0 : (cj == 1 ? (ci == 0 ? 1 : 3)
                                                            : (ci == 0 ? 2 : (ci == 1 ? 4 : 5)));
                    const int p3 = q * 3;
                    const float4 o = ov[ci];
                    acc[p3 + 0] = fmaf(o.x, prv,  acc[p3 + 0]);
                    acc[p3 + 0] = fmaf(o.y, bv.x, acc[p3 + 0]);
                    acc[p3 + 0] = fmaf(o.z, bv.y, acc[p3 + 0]);
                    acc[p3 + 0] = fmaf(o.w, bv.z, acc[p3 + 0]);
                    acc[p3 + 1] = fmaf(o.x, bv.x, acc[p3 + 1]);
                    acc[p3 + 1] = fmaf(o.y, bv.y, acc[p3 + 1]);
                    acc[p3 + 1] = fmaf(o.z, bv.z, acc[p3 + 1]);
                    acc[p3 + 1] = fmaf(o.w, bv.w, acc[p3 + 1]);
                    acc[p3 + 2] = fmaf(o.x, bv.y, acc[p3 + 2]);
                    acc[p3 + 2] = fmaf(o.y, bv.z, acc[p3 + 2]);
                    acc[p3 + 2] = fmaf(o.z, bv.w, acc[p3 + 2]);
                    acc[p3 + 2] = fmaf(o.w, nxt,  acc[p3 + 2]);
                }
            }

            // 4-lane pre-reduce over w4 (masks 1,2: quad-perm class)
            #pragma unroll
            for (int j = 0; j < 18; ++j) {
                acc[j] += __shfl_xor(acc[j], 1, 64);
                acc[j] += __shfl_xor(acc[j], 2, 64);
            }
            if ((tid & 3) == 0) {
                const int grp = tid >> 2;                 // 0..63
                float4* rb = reinterpret_cast<float4*>(&smem[SM_RBUF + grp * 20]);
                rb[0] = make_float4(acc[0],  acc[1],  acc[2],  acc[3]);
                rb[1] = make_float4(acc[4],  acc[5],  acc[6],  acc[7]);
                rb[2] = make_float4(acc[8],  acc[9],  acc[10], acc[11]);
                rb[3] = make_float4(acc[12], acc[13], acc[14], acc[15]);
                rb[4] = make_float4(acc[16], acc[17], 0.f, 0.f);
            }
            __syncthreads();             // A: rbuf visible
            if (tid < 80) {              // stage1: rows consecutive across lanes
                const int j4 = tid / 16, rblk = tid & 15;
                float4 s = make_float4(0.f, 0.f, 0.f, 0.f);
                #pragma unroll
                for (int k = 0; k < 4; ++k) {
                    const int r = rblk + k * 16;
                    s = add4(s, *reinterpret_cast<const float4*>(&smem[SM_RBUF + r * 20 + j4 * 4]));
                }
                *reinterpret_cast<float4*>(&smem[SM_RB2 + rblk * 20 + j4 * 4]) = s;
            }
            __syncthreads();             // B: RB2 visible (next rbuf write WAR-safe)
            if (tid < 18) {              // stage2
                float s = 0.f;
                #pragma unroll
                for (int r = 0; r < 16; ++r) s += smem[SM_RB2 + r * 20 + tid];
                smem[SM_REDA + ddh * 20 + tid] = s;
            }
        }
        __syncthreads();

        if (tid < 162) {
            const int q = tid / 27, rem = tid % 27;
            const int pass = rem / 3, dw = rem % 3;
            A3p[(size_t)ab_ * 162 + tid] = smem[SM_REDA + pass * 20 + q * 3 + dw];
        } else if (tid < 165) {
            const int ci = tid - 162;
            X3p[ab_ * 3 + ci] = smem[SM_REDX + ci] + smem[SM_REDX + 3 + ci] +
                                smem[SM_REDX + 6 + ci] + smem[SM_REDX + 9 + ci];
        }
    }
}

// ---------- reduce + expand symmetric A3 -> ordered 243 (+ X3) ----------
__global__ __launch_bounds__(256) void reduce_A3(
    const float* __restrict__ A3p, const float* __restrict__ X3p,
    float* __restrict__ A3r) {
    const int wv = blockIdx.x * 4 + (threadIdx.x >> 6);  // 0..247
    const int lane = threadIdx.x & 63;
    float s = 0.f;
    if (wv < 243) {
        const int p = wv / 27, lag = wv % 27;
        const int ci = p / 3, cj = p % 3;
        int q, l2;
        if (ci <= cj) {
            q = (ci == 0) ? cj : (ci == 1 ? 2 + cj : 5);
            l2 = lag;
        } else {
            q = (cj == 0) ? ci : 4;
            l2 = 26 - lag;
        }
        #pragma unroll
        for (int k = 0; k < 16; ++k)
            s += A3p[(size_t)(lane * 16 + k) * 162 + q * 27 + l2];
    } else if (wv < 246) {
        const int ci = wv - 243;
        #pragma unroll
        for (int k = 0; k < 16; ++k) s += X3p[(lane * 16 + k) * 3 + ci];
    }
    #pragma unroll
    for (int m = 1; m < 64; m <<= 1) s += __shfl_xor(s, m, 64);
    if (lane == 0 && wv < 246) A3r[wv] = s;
}

// ---------- finalize: combine A's with weight-pair sums -> ab ----------
__global__ __launch_bounds__(256) void finalize2(
    const float* __restrict__ x, const float* __restrict__ w,
    const float* __restrict__ gamma, const float* __restrict__ beta,
    const float* __restrict__ ws, float* __restrict__ ab) {
    const int tid = threadIdx.x;
    __shared__ float lw[1296];
    __shared__ float lA3[243], lX3[3], lA2[486], lX2[18], lA1[324], lX1[36];
    __shared__ float lxc[8][3][32];
    __shared__ float lA0[72], lX0[24];
    __shared__ float red2[144], red1[48];

    for (int i = tid; i < 1296; i += 256) lw[i] = w[i];
    if (tid < 243) lA3[tid] = ws[WS_A3R + tid];
    if (tid >= 243 && tid < 246) lX3[tid - 243] = ws[WS_A3R + tid];
    for (int i = tid; i < 486; i += 256) {
        const float* p = ws + WS_A2P + i * 32;
        float s = 0.f;
        #pragma unroll
        for (int nn = 0; nn < 32; ++nn) s += p[nn];
        lA2[i] = s;
    }
    if (tid < 18) {
        const float* p = ws + WS_X2P + tid * 32;
        float s = 0.f;
        for (int nn = 0; nn < 32; ++nn) s += p[nn];
        lX2[tid] = s;
    }
    for (int i = tid; i < 324; i += 256) lA1[i] = ws[WS_A1 + i];
    if (tid < 36) lX1[tid] = ws[WS_X1 + tid];
    for (int i = tid; i < 768; i += 256) {
        const int c = i / 96, ci = (i / 32) % 3, nn = i % 32;
        const int off = (((c >> 2) & 1) ? 31 : 0) * 1024 +
                        (((c >> 1) & 1) ? 31 : 0) * 32 + ((c & 1) ? 31 : 0);
        lxc[c][ci][nn] = x[(size_t)nn * NS + ci * I3 + off];
    }
    __syncthreads();
    if (tid < 72) {
        const int c = tid / 9, p = tid % 9, ci = p / 3, cj = p % 3;
        float s = 0.f;
        for (int nn = 0; nn < 32; ++nn) s += lxc[c][ci][nn] * lxc[c][cj][nn];
        lA0[tid] = s;
    }
    if (tid >= 72 && tid < 96) {
        const int t = tid - 72, c = t / 3, ci = t % 3;
        float s = 0.f;
        for (int nn = 0; nn < 32; ++nn) s += lxc[c][ci][nn];
        lX0[t] = s;
    }
    __syncthreads();

    const int KPn[3] = {1, 3, 1};
    const int KPa[3][3] = {{0, 0, 0}, {0, 1, 2}, {2, 0, 0}};
    const int KPb[3][3] = {{2, 0, 0}, {0, 1, 2}, {0, 0, 0}};

    if (tid < 144) {
        const int co = tid / 9, p = tid % 9, ci = p / 3, cj = p % 3;
        const float* wi = lw + (ci * 16 + co) * 27;
        const float* wj = lw + (cj * 16 + co) * 27;
        float tot = 0.f;
        for (int dd = 0; dd < 3; ++dd)
            for (int dh = 0; dh < 3; ++dh)
                for (int dw = 0; dw < 3; ++dw) {
                    float sw = 0.f;
                    for (int a = 0; a < KPn[dd]; ++a)
                        for (int b = 0; b < KPn[dh]; ++b)
                            for (int c = 0; c < KPn[dw]; ++c)
                                sw += wi[KPa[dd][a] * 9 + KPa[dh][b] * 3 + KPa[dw][c]] *
                                      wj[KPb[dd][a] * 9 + KPb[dh][b] * 3 + KPb[dw][c]];
                    tot += lA3[p * 27 + dd * 9 + dh * 3 + dw] * sw;
                }
        for (int f = 0; f < 6; ++f) {
            const int s = f >> 1, c = (f & 1) ? 2 : 0;
            float fsum = 0.f;
            for (int du = 0; du < 3; ++du)
                for (int dv = 0; dv < 3; ++dv) {
                    float sw = 0.f;
                    for (int a = 0; a < KPn[du]; ++a)
                        for (int b = 0; b < KPn[dv]; ++b) {
                            const int ku = KPa[du][a], kup = KPb[du][a];
                            const int kv = KPa[dv][b], kvp = KPb[dv][b];
                            int ii, jj;
                            if (s == 0)      { ii = c * 9 + ku * 3 + kv;  jj = c * 9 + kup * 3 + kvp; }
                            else if (s == 1) { ii = ku * 9 + c * 3 + kv;  jj = kup * 9 + c * 3 + kvp; }
                            else             { ii = ku * 9 + kv * 3 + c;  jj = kup * 9 + kvp * 3 + c; }
                            sw += wi[ii] * wj[jj];
                        }
                    fsum += lA2[(f * 9 + p) * 9 + du * 3 + dv] * sw;
                }
            tot -= fsum;
        }
        for (int e12 = 0; e12 < 12; ++e12) {
            const int dp = e12 >> 2;
            const int c1 = ((e12 >> 1) & 1) ? 2 : 0, c2 = (e12 & 1) ? 2 : 0;
            float esum = 0.f;
            for (int dt = 0; dt < 3; ++dt) {
                float sw = 0.f;
                for (int a = 0; a < KPn[dt]; ++a) {
                    const int kt = KPa[dt][a], ktp = KPb[dt][a];
                    int ii, jj;
                    if (dp == 0)      { ii = c1 * 9 + c2 * 3 + kt; jj = c1 * 9 + c2 * 3 + ktp; }
                    else if (dp == 1) { ii = c1 * 9 + kt * 3 + c2; jj = c1 * 9 + ktp * 3 + c2; }
                    else              { ii = kt * 9 + c1 * 3 + c2; jj = ktp * 9 + c1 * 3 + c2; }
                    sw += wi[ii] * wj[jj];
                }
                esum += lA1[(e12 * 9 + p) * 3 + dt] * sw;
            }
            tot += esum;
        }
        for (int c = 0; c < 8; ++c) {
            const int kk = (((c >> 2) & 1) ? 2 : 0) * 9 +
                           (((c >> 1) & 1) ? 2 : 0) * 3 + ((c & 1) ? 2 : 0);
            tot -= lA0[c * 9 + p] * wi[kk] * wj[kk];
        }
        red2[tid] = tot;
    }
    if (tid >= 144 && tid < 192) {
        const int t = tid - 144, co = t / 3, ci = t % 3;
        const float* wi = lw + (ci * 16 + co) * 27;
        float lw3 = 0.f;
        for (int k = 0; k < 27; ++k) lw3 += wi[k];
        float tot = lX3[ci] * lw3;
        for (int f = 0; f < 6; ++f) {
            const int s = f >> 1, c = (f & 1) ? 2 : 0;
            float l2 = 0.f;
            for (int ku = 0; ku < 3; ++ku)
                for (int kv = 0; kv < 3; ++kv) {
                    const int ii = (s == 0) ? c * 9 + ku * 3 + kv
                                 : (s == 1) ? ku * 9 + c * 3 + kv
                                            : ku * 9 + kv * 3 + c;
                    l2 += wi[ii];
                }
            tot -= lX2[f * 3 + ci] * l2;
        }
        for (int e12 = 0; e12 < 12; ++e12) {
            const int dp = e12 >> 2;
            const int c1 = ((e12 >> 1) & 1) ? 2 : 0, c2 = (e12 & 1) ? 2 : 0;
            float l1 = 0.f;
            for (int kt = 0; kt < 3; ++kt) {
                const int ii = (dp == 0) ? c1 * 9 + c2 * 3 + kt
                             : (dp == 1) ? c1 * 9 + kt * 3 + c2
                                         : kt * 9 + c1 * 3 + c2;
                l1 += wi[ii];
            }
            tot += lX1[e12 * 3 + ci] * l1;
        }
        for (int c = 0; c < 8; ++c) {
            const int kk = (((c >> 2) & 1) ? 2 : 0) * 9 +
                           (((c >> 1) & 1) ? 2 : 0) * 3 + ((c & 1) ? 2 : 0);
            tot -= lX0[c * 3 + ci] * wi[kk];
        }
        red1[t] = tot;
    }
    __syncthreads();
    if (tid < 16) {
        float S2 = 0.f;
        for (int p = 0; p < 9; ++p) S2 += red2[tid * 9 + p];
        const float S1 = red1[tid * 3] + red1[tid * 3 + 1] + red1[tid * 3 + 2];
        const float mean = S1 / COUNT_Y;
        const float var = S2 / COUNT_Y - mean * mean;
        const float invg = rsqrtf(var + 1e-5f) * gamma[tid];
        ab[tid] = invg * (1.0f / 64.0f);
        ab[16 + tid] = beta[tid] - mean * invg;
    }
}

// ---------- pooled conv + norm (runs last) ----------
__global__ __launch_bounds__(256, 4) void pooled_norm(
    const float* __restrict__ x, const float* __restrict__ G,
    const float* __restrict__ ab, float* __restrict__ out) {
    const int pd = blockIdx.x >> 1, coh = blockIdx.x & 1, n = blockIdx.y;
    const int tid = threadIdx.x;
    if (tid >= 225) return;
    const int ph = tid / 15, pw = tid % 15;
    const float* xn = x + (size_t)n * NS;
    float acc[8] = {};
    #pragma unroll
    for (int ci = 0; ci < 3; ++ci) {
        float xl[27];
        const float* xc = xn + ci * I3 + (2 * pd) * 1024 + (2 * ph) * 32 + 2 * pw;
        #pragma unroll
        for (int jd = 0; jd < 3; ++jd)
            #pragma unroll
            for (int jh = 0; jh < 3; ++jh) {
                const float* r = xc + jd * 1024 + jh * 32;
                const float2 f2 = *reinterpret_cast<const float2*>(r);
                xl[jd * 9 + jh * 3 + 0] = f2.x;
                xl[jd * 9 + jh * 3 + 1] = f2.y;
                xl[jd * 9 + jh * 3 + 2] = r[2];
            }
        #pragma unroll
        for (int c8 = 0; c8 < 8; ++c8) {
            const float* gp = G + (ci * 16 + coh * 8 + c8) * 27;
            #pragma unroll
            for (int j = 0; j < 27; ++j)
                acc[c8] = fmaf(gp[j], xl[j], acc[c8]);
        }
    }
    const int ob = (n * 16 + coh * 8) * POOL3 + pd * 225 + ph * 15 + pw;
    #pragma unroll
    for (int c8 = 0; c8 < 8; ++c8) {
        const int co = coh * 8 + c8;
        out[ob + c8 * POOL3] = fmaf(acc[c8], ab[co], ab[16 + co]);
    }
}

extern "C" void kernel_launch(void* const* d_in, const int* in_sizes, int n_in,
                              void* d_out, int out_size, void* d_ws, size_t ws_size,
                              hipStream_t stream) {
    const float* x     = (const float*)d_in[0];
    const float* w     = (const float*)d_in[1];
    const float* gamma = (const float*)d_in[2];
    const float* beta  = (const float*)d_in[3];
    float* out = (float*)d_out;
    float* ws  = (float*)d_ws;

    mega_k<<<1234, 256, 0, stream>>>(x, w, ws + WS_A3P, ws + WS_X3P,
                                     ws + WS_A2P, ws + WS_X2P,
                                     ws + WS_A1, ws + WS_X1, ws + WS_G);
    reduce_A3<<<62, 256, 0, stream>>>(ws + WS_A3P, ws + WS_X3P, ws + WS_A3R);
    finalize2<<<1, 256, 0, stream>>>(x, w, gamma, beta, ws, ws + WS_AB);
    pooled_norm<<<dim3(30, 32), 256, 0, stream>>>(x, ws + WS_G, ws + WS_AB, out);
}

// Round 16
// 69.492 us; speedup vs baseline: 1.0041x; 1.0041x over previous
//
#include <hip/hip_runtime.h>

// ConvTranspose3d(3->16,k=3,s=2,p=1) + per-channel BN-norm + 2x avgpool2, fully fused.
// Identity 1: pooled output = stride-2 3^3 conv of x with collapsed kernel G (+norm inline).
// Identity 2: sum(y), sum(y^2) via x-autocorrelation at 27 lags + inclusion-exclusion
// boundary corrections (faces/edges/corners).
// R16: barrier-free autocorr pass loop. Full-width w rows (physical-zero edges, no
// halo), XOR-swizzled LDS, 4-round shfl pre-reduce, per-pass partials written
// straight to global (transposed, coalesced reduce). 4 launches.

#define I3 32768
#define NS 98304              // n stride in x = 3*32768
#define COUNT_Y 8001504.0f    // 32*63^3
#define POOL3 3375
#define TOTAL_OUT 1728000

// ws layout (floats)
#define WS_G    0              // 1296
#define WS_A3P  1296           // 512 blk * 9 pass * 18 j * 16 g = 1,327,104
#define WS_X3P  1328400        // 512*3 = 1536
#define WS_A2P  1329936        // 486*32 = 15552
#define WS_X2P  1345488        // 18*32 = 576
#define WS_A1   1346064        // 324
#define WS_X1   1346388        // 36
#define WS_A3R  1346424        // 246
#define WS_AB   1346670        // 32   -> 1,346,702 floats ~ 5.4 MB

// mega smem: XS [12 cp][34 h][8 f4] = 13056 fl ; redX 12 -> 52,272 B (3 blocks/CU)
#define SM_REDX 13056
#define SM_TOT  13068

// ---------- mega: faces(192) + edges(12) + prep_G(6) + autocorr(512) ----------
__global__ __launch_bounds__(256, 3) void mega_k(
    const float* __restrict__ x, const float* __restrict__ w,
    float* __restrict__ A3p, float* __restrict__ X3p,
    float* __restrict__ A2P, float* __restrict__ X2P,
    float* __restrict__ A1, float* __restrict__ X1,
    float* __restrict__ G)
{
    const int b = blockIdx.x;
    const int tid = threadIdx.x;
    __shared__ float smem[SM_TOT];

    #define PL(ci,u,v) smem[((ci)*32+(u))*33+(v)]
    if (b < 192) {
        // ======== faces ========
        const int f = b >> 5, n = b & 31;
        const int s = f >> 1, e = (f & 1) ? 31 : 0;
        int su, sv, off;
        if (s == 0)      { su = 32;   sv = 1;  off = e * 1024; }
        else if (s == 1) { su = 1024; sv = 1;  off = e * 32;   }
        else             { su = 1024; sv = 32; off = e;        }
        const float* xb = x + (size_t)n * NS + off;
        for (int idx = tid; idx < 3072; idx += 256) {
            const int ci = idx >> 10, r = idx & 1023, u = r >> 5, v = r & 31;
            PL(ci, u, v) = xb[ci * I3 + u * su + v * sv];
        }
        __syncthreads();
        const int grp = tid >> 5, u = tid & 31;
        #pragma unroll 1
        for (int j = grp; j < 84; j += 8) {
            float t2 = 0.f;
            if (j < 81) {
                const int p = j / 9, lag = j % 9;
                const int du = lag / 3 - 1, dv = lag % 3 - 1;
                const int ci = p / 3, cj = p % 3;
                const int un = u + du;
                if ((unsigned)un < 32u) {
                    const int vlo = (dv == -1) ? 1 : 0, vhi = (dv == 1) ? 30 : 31;
                    const float* ro = &PL(ci, u, 0);
                    const float* rn = &PL(cj, un, dv);
                    for (int v = vlo; v <= vhi; ++v) t2 = fmaf(ro[v], rn[v], t2);
                }
            } else {
                const int ci = j - 81;
                for (int v = 0; v < 32; ++v) t2 += PL(ci, u, v);
            }
            #pragma unroll
            for (int m = 1; m < 32; m <<= 1) t2 += __shfl_xor(t2, m, 32);
            if (u == 0) {
                if (j < 81) A2P[(f * 81 + j) * 32 + n] = t2;
                else        X2P[(f * 3 + (j - 81)) * 32 + n] = t2;
            }
        }
        return;
    }

    if (b < 204) {
        // ======== edges ========
        const int e12 = b - 192;
        const int dp = e12 >> 2;
        const int e1 = ((e12 >> 1) & 1) ? 31 : 0, e2 = (e12 & 1) ? 31 : 0;
        int st_, off;
        if (dp == 0)      { st_ = 1;    off = e1 * 1024 + e2 * 32; }
        else if (dp == 1) { st_ = 32;   off = e1 * 1024 + e2;      }
        else              { st_ = 1024; off = e1 * 32 + e2;        }
        for (int idx = tid; idx < 3072; idx += 256) {
            const int ci = idx >> 10, r = idx & 1023, n = r >> 5, v = r & 31;
            PL(ci, n, v) = x[(size_t)n * NS + ci * I3 + off + v * st_];
        }
        __syncthreads();
        const int grp = tid >> 5, n2 = tid & 31;
        #pragma unroll 1
        for (int j = grp; j < 30; j += 8) {
            float t = 0.f;
            if (j < 27) {
                const int p = j / 3, dt = j % 3 - 1;
                const int ci = p / 3, cj = p % 3;
                const int vlo = (dt == -1) ? 1 : 0, vhi = (dt == 1) ? 30 : 31;
                const float* ro = &PL(ci, n2, 0);
                const float* rn = &PL(cj, n2, dt);
                for (int v = vlo; v <= vhi; ++v) t = fmaf(ro[v], rn[v], t);
            } else {
                const int ci = j - 27;
                for (int v = 0; v < 32; ++v) t += PL(ci, n2, v);
            }
            #pragma unroll
            for (int m = 1; m < 32; m <<= 1) t += __shfl_xor(t, m, 32);
            if (n2 == 0) {
                if (j < 27) A1[e12 * 27 + j] = t;
                else        X1[e12 * 3 + (j - 27)] = t;
            }
        }
        return;
    }

    if (b < 210) {
        // ======== prep_G ========
        const int idx = (b - 204) * 256 + tid;
        if (idx >= 1296) return;
        const int ci = idx / 432, rem = idx % 432, co = rem / 27, j = rem % 27;
        const int jd = j / 9, jh = (j / 3) % 3, jw = j % 3;
        const int SLEN[3] = {2, 3, 1};
        const int SK[3][3] = {{1, 2, 0}, {0, 1, 2}, {0, 0, 0}};
        const float* wp = w + (ci * 16 + co) * 27;
        float s = 0.f;
        for (int a = 0; a < SLEN[jd]; ++a)
            for (int bq = 0; bq < SLEN[jh]; ++bq)
                for (int c = 0; c < SLEN[jw]; ++c)
                    s += wp[SK[jd][a] * 9 + SK[jh][bq] * 3 + SK[jw][c]];
        G[idx] = s;
        return;
    }

    // ======== 3D autocorrelation: 2-plane slab, full-w rows, barrier-free loop ====
    {
        const int ab_ = b - 210;            // 0..511
        const int dblk = ab_ >> 5, n = ab_ & 31;
        const int d0 = dblk * 2;
        const int w8 = tid & 3;             // 8-float chunk (w = w8*8..w8*8+7)
        const int h  = (tid >> 2) & 31;
        const int dth = tid >> 7;           // 0..1 own d-plane
        const int dp_own = 1 + dth;
        const int lane = tid & 63, wave = tid >> 6;

        // XS float4 index: ((cp*34 + hh)*8 + cc)*4 ; cc = c ^ (hh&7)  (bank spread)
        // zero pad rows hh = 0, 33 (12 cp * 2 rows * 8 c = 192 f4)
        if (tid < 192) {
            const int c = tid & 7, rr = (tid >> 3) & 1, cp = tid >> 4;
            const int row = rr ? 33 : 0;
            *reinterpret_cast<float4*>(&smem[((cp * 34 + row) * 8 + c) * 4]) =
                make_float4(0.f, 0.f, 0.f, 0.f);
        }

        // register-staged main load: 12 float4/thread (3ci*4dp*32h*8c = 3072 f4)
        float4 st[12];
        #pragma unroll
        for (int k = 0; k < 12; ++k) {
            const int i = tid + k * 256;
            const int c = i & 7, hh = (i >> 3) & 31, cp = i >> 8;
            const int dp = cp & 3, ci = cp >> 2;
            const int d = d0 - 1 + dp;
            const bool v = ((unsigned)d < 32u);
            const float4 f = *reinterpret_cast<const float4*>(
                x + (size_t)n * NS + ci * I3 + (v ? d : 0) * 1024 + hh * 32 + c * 4);
            st[k] = v ? f : make_float4(0.f, 0.f, 0.f, 0.f);
        }
        #pragma unroll
        for (int k = 0; k < 12; ++k) {
            const int i = tid + k * 256;
            const int c = i & 7, hh = (i >> 3) & 31, cp = i >> 8;
            const int cc = c ^ ((hh + 1) & 7);
            *reinterpret_cast<float4*>(&smem[((cp * 34 + hh + 1) * 8 + cc) * 4]) = st[k];
        }
        __syncthreads();

        // hoisted own-plane loads (2 f4 per ci) + X sums
        float4 ov0[3], ov1[3];
        {
            const int sw = (h + 1) & 7;
            #pragma unroll
            for (int ci = 0; ci < 3; ++ci) {
                const int cp = ci * 4 + dp_own;
                ov0[ci] = *reinterpret_cast<const float4*>(
                    &smem[((cp * 34 + h + 1) * 8 + ((w8 * 2) ^ sw)) * 4]);
                ov1[ci] = *reinterpret_cast<const float4*>(
                    &smem[((cp * 34 + h + 1) * 8 + ((w8 * 2 + 1) ^ sw)) * 4]);
            }
        }
        {
            float sx[3];
            #pragma unroll
            for (int ci = 0; ci < 3; ++ci)
                sx[ci] = ov0[ci].x + ov0[ci].y + ov0[ci].z + ov0[ci].w +
                         ov1[ci].x + ov1[ci].y + ov1[ci].z + ov1[ci].w;
            #pragma unroll
            for (int m = 1; m < 64; m <<= 1) {
                sx[0] += __shfl_xor(sx[0], m, 64);
                sx[1] += __shfl_xor(sx[1], m, 64);
                sx[2] += __shfl_xor(sx[2], m, 64);
            }
            if (lane == 0) {
                smem[SM_REDX + wave * 3 + 0] = sx[0];
                smem[SM_REDX + wave * 3 + 1] = sx[1];
                smem[SM_REDX + wave * 3 + 2] = sx[2];
            }
            __syncthreads();
            if (tid < 3)
                X3p[ab_ * 3 + tid] = smem[SM_REDX + tid] + smem[SM_REDX + 3 + tid] +
                                     smem[SM_REDX + 6 + tid] + smem[SM_REDX + 9 + tid];
        }

        // ---- 9 passes, NO barriers ----
        const size_t pbase = (size_t)ab_ * 9;
        #pragma unroll 1
        for (int pass = 0; pass < 9; ++pass) {
            const int dd = pass / 3 - 1, dh = pass % 3 - 1;
            const int hn = h + 1 + dh;
            const int dpo = dp_own + dd;
            const int swn = hn & 7;
            float acc[18];
            #pragma unroll
            for (int j = 0; j < 18; ++j) acc[j] = 0.f;

            #pragma unroll
            for (int cj = 0; cj < 3; ++cj) {
                const int cp2 = cj * 4 + dpo;
                const float4 b0 = *reinterpret_cast<const float4*>(
                    &smem[((cp2 * 34 + hn) * 8 + ((w8 * 2) ^ swn)) * 4]);
                const float4 b1 = *reinterpret_cast<const float4*>(
                    &smem[((cp2 * 34 + hn) * 8 + ((w8 * 2 + 1) ^ swn)) * 4]);
                float nxt = __shfl(b0.x, lane + 1, 64);
                float prv = __shfl(b1.w, lane - 1, 64);
                if (w8 == 3) nxt = 0.f;   // w=31 physical edge
                if (w8 == 0) prv = 0.f;   // w=0  physical edge
                #pragma unroll
                for (int ci = 0; ci <= cj; ++ci) {
                    const int q = (cj == 0) ? 0 : (cj == 1 ? (ci == 0 ? 1 : 3)
                                                            : (ci == 0 ? 2 : (ci == 1 ? 4 : 5)));
                    const int p3 = q * 3;
                    const float4 o0 = ov0[ci], o1 = ov1[ci];
                    // dw = 0
                    acc[p3 + 1] = fmaf(o0.x, b0.x, acc[p3 + 1]);
                    acc[p3 + 1] = fmaf(o0.y, b0.y, acc[p3 + 1]);
                    acc[p3 + 1] = fmaf(o0.z, b0.z, acc[p3 + 1]);
                    acc[p3 + 1] = fmaf(o0.w, b0.w, acc[p3 + 1]);
                    acc[p3 + 1] = fmaf(o1.x, b1.x, acc[p3 + 1]);
                    acc[p3 + 1] = fmaf(o1.y, b1.y, acc[p3 + 1]);
                    acc[p3 + 1] = fmaf(o1.z, b1.z, acc[p3 + 1]);
                    acc[p3 + 1] = fmaf(o1.w, b1.w, acc[p3 + 1]);
                    // dw = +1
                    acc[p3 + 2] = fmaf(o0.x, b0.y, acc[p3 + 2]);
                    acc[p3 + 2] = fmaf(o0.y, b0.z, acc[p3 + 2]);
                    acc[p3 + 2] = fmaf(o0.z, b0.w, acc[p3 + 2]);
                    acc[p3 + 2] = fmaf(o0.w, b1.x, acc[p3 + 2]);
                    acc[p3 + 2] = fmaf(o1.x, b1.y, acc[p3 + 2]);
                    acc[p3 + 2] = fmaf(o1.y, b1.z, acc[p3 + 2]);
                    acc[p3 + 2] = fmaf(o1.z, b1.w, acc[p3 + 2]);
                    acc[p3 + 2] = fmaf(o1.w, nxt,  acc[p3 + 2]);
                    // dw = -1
                    acc[p3 + 0] = fmaf(o0.x, prv,  acc[p3 + 0]);
                    acc[p3 + 0] = fmaf(o0.y, b0.x, acc[p3 + 0]);
                    acc[p3 + 0] = fmaf(o0.z, b0.y, acc[p3 + 0]);
                    acc[p3 + 0] = fmaf(o0.w, b0.z, acc[p3 + 0]);
                    acc[p3 + 0] = fmaf(o1.x, b0.w, acc[p3 + 0]);
                    acc[p3 + 0] = fmaf(o1.y, b1.x, acc[p3 + 0]);
                    acc[p3 + 0] = fmaf(o1.z, b1.y, acc[p3 + 0]);
                    acc[p3 + 0] = fmaf(o1.w, b1.z, acc[p3 + 0]);
                }
            }

            // 4-round pre-reduce: sums 4 w-chunks x 4 h -> 16 groups/block
            #pragma unroll
            for (int j = 0; j < 18; ++j) {
                acc[j] += __shfl_xor(acc[j], 1, 64);
                acc[j] += __shfl_xor(acc[j], 2, 64);
                acc[j] += __shfl_xor(acc[j], 4, 64);
                acc[j] += __shfl_xor(acc[j], 8, 64);
            }
            if ((tid & 15) == 0) {
                float* dst = A3p + (pbase + pass) * 288 + (tid >> 4);  // 18*16 per (blk,pass)
                #pragma unroll
                for (int j = 0; j < 18; ++j) dst[j * 16] = acc[j];
            }
        }
    }
}

// ---------- reduce + expand symmetric A3 -> ordered 243 (+ X3) ----------
__global__ __launch_bounds__(256) void reduce_A3(
    const float* __restrict__ A3p, const float* __restrict__ X3p,
    float* __restrict__ A3r) {
    const int wv = blockIdx.x * 4 + (threadIdx.x >> 6);  // 0..247
    const int lane = threadIdx.x & 63;
    float s = 0.f;
    if (wv < 243) {
        const int p = wv / 27, lag = wv % 27;
        const int ci = p / 3, cj = p % 3;
        int q, l2;
        if (ci <= cj) {
            q = (ci == 0) ? cj : (ci == 1 ? 2 + cj : 5);
            l2 = lag;
        } else {
            q = (cj == 0) ? ci : 4;
            l2 = 26 - lag;
        }
        const int pass = l2 / 3, dw = l2 % 3, j = q * 3 + dw;
        const int g = lane & 15, bo = lane >> 4;
        const int base = (pass * 18 + j) * 16 + g;
        #pragma unroll 4
        for (int it = 0; it < 128; ++it) {
            const int blk = it * 4 + bo;
            s += A3p[(size_t)blk * 2592 + base];
        }
    } else if (wv < 246) {
        const int ci = wv - 243;
        #pragma unroll
        for (int k = 0; k < 8; ++k) s += X3p[(lane * 8 + k) * 3 + ci];
    }
    #pragma unroll
    for (int m = 1; m < 64; m <<= 1) s += __shfl_xor(s, m, 64);
    if (lane == 0 && wv < 246) A3r[wv] = s;
}

// ---------- finalize: combine A's with weight-pair sums -> ab ----------
__global__ __launch_bounds__(256) void finalize2(
    const float* __restrict__ x, const float* __restrict__ w,
    const float* __restrict__ gamma, const float* __restrict__ beta,
    const float* __restrict__ ws, float* __restrict__ ab) {
    const int tid = threadIdx.x;
    __shared__ float lw[1296];
    __shared__ float lA3[243], lX3[3], lA2[486], lX2[18], lA1[324], lX1[36];
    __shared__ float lxc[8][3][32];
    __shared__ float lA0[72], lX0[24];
    __shared__ float red2[144], red1[48];

    for (int i = tid; i < 1296; i += 256) lw[i] = w[i];
    if (tid < 243) lA3[tid] = ws[WS_A3R + tid];
    if (tid >= 243 && tid < 246) lX3[tid - 243] = ws[WS_A3R + tid];
    for (int i = tid; i < 486; i += 256) {
        const float* p = ws + WS_A2P + i * 32;
        float s = 0.f;
        #pragma unroll
        for (int nn = 0; nn < 32; ++nn) s += p[nn];
        lA2[i] = s;
    }
    if (tid < 18) {
        const float* p = ws + WS_X2P + tid * 32;
        float s = 0.f;
        for (int nn = 0; nn < 32; ++nn) s += p[nn];
        lX2[tid] = s;
    }
    for (int i = tid; i < 324; i += 256) lA1[i] = ws[WS_A1 + i];
    if (tid < 36) lX1[tid] = ws[WS_X1 + tid];
    for (int i = tid; i < 768; i += 256) {
        const int c = i / 96, ci = (i / 32) % 3, nn = i % 32;
        const int off = (((c >> 2) & 1) ? 31 : 0) * 1024 +
                        (((c >> 1) & 1) ? 31 : 0) * 32 + ((c & 1) ? 31 : 0);
        lxc[c][ci][nn] = x[(size_t)nn * NS + ci * I3 + off];
    }
    __syncthreads();
    if (tid < 72) {
        const int c = tid / 9, p = tid % 9, ci = p / 3, cj = p % 3;
        float s = 0.f;
        for (int nn = 0; nn < 32; ++nn) s += lxc[c][ci][nn] * lxc[c][cj][nn];
        lA0[tid] = s;
    }
    if (tid >= 72 && tid < 96) {
        const int t = tid - 72, c = t / 3, ci = t % 3;
        float s = 0.f;
        for (int nn = 0; nn < 32; ++nn) s += lxc[c][ci][nn];
        lX0[t] = s;
    }
    __syncthreads();

    const int KPn[3] = {1, 3, 1};
    const int KPa[3][3] = {{0, 0, 0}, {0, 1, 2}, {2, 0, 0}};
    const int KPb[3][3] = {{2, 0, 0}, {0, 1, 2}, {0, 0, 0}};

    if (tid < 144) {
        const int co = tid / 9, p = tid % 9, ci = p / 3, cj = p % 3;
        const float* wi = lw + (ci * 16 + co) * 27;
        const float* wj = lw + (cj * 16 + co) * 27;
        float tot = 0.f;
        for (int dd = 0; dd < 3; ++dd)
            for (int dh = 0; dh < 3; ++dh)
                for (int dw = 0; dw < 3; ++dw) {
                    float sw = 0.f;
                    for (int a = 0; a < KPn[dd]; ++a)
                        for (int b = 0; b < KPn[dh]; ++b)
                            for (int c = 0; c < KPn[dw]; ++c)
                                sw += wi[KPa[dd][a] * 9 + KPa[dh][b] * 3 + KPa[dw][c]] *
                                      wj[KPb[dd][a] * 9 + KPb[dh][b] * 3 + KPb[dw][c]];
                    tot += lA3[p * 27 + dd * 9 + dh * 3 + dw] * sw;
                }
        for (int f = 0; f < 6; ++f) {
            const int s = f >> 1, c = (f & 1) ? 2 : 0;
            float fsum = 0.f;
            for (int du = 0; du < 3; ++du)
                for (int dv = 0; dv < 3; ++dv) {
                    float sw = 0.f;
                    for (int a = 0; a < KPn[du]; ++a)
                        for (int b = 0; b < KPn[dv]; ++b) {
                            const int ku = KPa[du][a], kup = KPb[du][a];
                            const int kv = KPa[dv][b], kvp = KPb[dv][b];
                            int ii, jj;
                            if (s == 0)      { ii = c * 9 + ku * 3 + kv;  jj = c * 9 + kup * 3 + kvp; }
                            else if (s == 1) { ii = ku * 9 + c * 3 + kv;  jj = kup * 9 + c * 3 + kvp; }
                            else             { ii = ku * 9 + kv * 3 + c;  jj = kup * 9 + kvp * 3 + c; }
                            sw += wi[ii] * wj[jj];
                        }
                    fsum += lA2[(f * 9 + p) * 9 + du * 3 + dv] * sw;
                }
            tot -= fsum;
        }
        for (int e12 = 0; e12 < 12; ++e12) {
            const int dp = e12 >> 2;
            const int c1 = ((e12 >> 1) & 1) ? 2 : 0, c2 = (e12 & 1) ? 2 : 0;
            float esum = 0.f;
            for (int dt = 0; dt < 3; ++dt) {
                float sw = 0.f;
                for (int a = 0; a < KPn[dt]; ++a) {
                    const int kt = KPa[dt][a], ktp = KPb[dt][a];
                    int ii, jj;
                    if (dp == 0)      { ii = c1 * 9 + c2 * 3 + kt; jj = c1 * 9 + c2 * 3 + ktp; }
                    else if (dp == 1) { ii = c1 * 9 + kt * 3 + c2; jj = c1 * 9 + ktp * 3 + c2; }
                    else              { ii = kt * 9 + c1 * 3 + c2; jj = ktp * 9 + c1 * 3 + c2; }
                    sw += wi[ii] * wj[jj];
                }
                esum += lA1[(e12 * 9 + p) * 3 + dt] * sw;
            }
            tot += esum;
        }
        for (int c = 0; c < 8; ++c) {
            const int kk = (((c >> 2) & 1) ? 2 : 0) * 9 +
                           (((c >> 1) & 1) ? 2 : 0) * 3 + ((c & 1) ? 2 : 0);
            tot -= lA0[c * 9 + p] * wi[kk] * wj[kk];
        }
        red2[tid] = tot;
    }
    if (tid >= 144 && tid < 192) {
        const int t = tid - 144, co = t / 3, ci = t % 3;
        const float* wi = lw + (ci * 16 + co) * 27;
        float lw3 = 0.f;
        for (int k = 0; k < 27; ++k) lw3 += wi[k];
        float tot = lX3[ci] * lw3;
        for (int f = 0; f < 6; ++f) {
            const int s = f >> 1, c = (f & 1) ? 2 : 0;
            float l2 = 0.f;
            for (int ku = 0; ku < 3; ++ku)
                for (int kv = 0; kv < 3; ++kv) {
                    const int ii = (s == 0) ? c * 9 + ku * 3 + kv
                                 : (s == 1) ? ku * 9 + c * 3 + kv
                                            : ku * 9 + kv * 3 + c;
                    l2 += wi[ii];
                }
            tot -= lX2[f * 3 + ci] * l2;
        }
        for (int e12 = 0; e12 < 12; ++e12) {
            const int dp = e12 >> 2;
            const int c1 = ((e12 >> 1) & 1) ? 2 : 0, c2 = (e12 & 1) ? 2 : 0;
            float l1 = 0.f;
            for (int kt = 0; kt < 3; ++kt) {
                const int ii = (dp == 0) ? c1 * 9 + c2 * 3 + kt
                             : (dp == 1) ? c1 * 9 + kt * 3 + c2
                                         : kt * 9 + c1 * 3 + c2;
                l1 += wi[ii];
            }
            tot += lX1[e12 * 3 + ci] * l1;
        }
        for (int c = 0; c < 8; ++c) {
            const int kk = (((c >> 2) & 1) ? 2 : 0) * 9 +
                           (((c >> 1) & 1) ? 2 : 0) * 3 + ((c & 1) ? 2 : 0);
            tot -= lX0[c * 3 + ci] * wi[kk];
        }
        red1[t] = tot;
    }
    __syncthreads();
    if (tid < 16) {
        float S2 = 0.f;
        for (int p = 0; p < 9; ++p) S2 += red2[tid * 9 + p];
        const float S1 = red1[tid * 3] + red1[tid * 3 + 1] + red1[tid * 3 + 2];
        const float mean = S1 / COUNT_Y;
        const float var = S2 / COUNT_Y - mean * mean;
        const float invg = rsqrtf(var + 1e-5f) * gamma[tid];
        ab[tid] = invg * (1.0f / 64.0f);
        ab[16 + tid] = beta[tid] - mean * invg;
    }
}

// ---------- pooled conv + norm (runs last) ----------
__global__ __launch_bounds__(256, 4) void pooled_norm(
    const float* __restrict__ x, const float* __restrict__ G,
    const float* __restrict__ ab, float* __restrict__ out) {
    const int pd = blockIdx.x >> 1, coh = blockIdx.x & 1, n = blockIdx.y;
    const int tid = threadIdx.x;
    if (tid >= 225) return;
    const int ph = tid / 15, pw = tid % 15;
    const float* xn = x + (size_t)n * NS;
    float acc[8] = {};
    #pragma unroll
    for (int ci = 0; ci < 3; ++ci) {
        float xl[27];
        const float* xc = xn + ci * I3 + (2 * pd) * 1024 + (2 * ph) * 32 + 2 * pw;
        #pragma unroll
        for (int jd = 0; jd < 3; ++jd)
            #pragma unroll
            for (int jh = 0; jh < 3; ++jh) {
                const float* r = xc + jd * 1024 + jh * 32;
                const float2 f2 = *reinterpret_cast<const float2*>(r);
                xl[jd * 9 + jh * 3 + 0] = f2.x;
                xl[jd * 9 + jh * 3 + 1] = f2.y;
                xl[jd * 9 + jh * 3 + 2] = r[2];
            }
        #pragma unroll
        for (int c8 = 0; c8 < 8; ++c8) {
            const float* gp = G + (ci * 16 + coh * 8 + c8) * 27;
            #pragma unroll
            for (int j = 0; j < 27; ++j)
                acc[c8] = fmaf(gp[j], xl[j], acc[c8]);
        }
    }
    const int ob = (n * 16 + coh * 8) * POOL3 + pd * 225 + ph * 15 + pw;
    #pragma unroll
    for (int c8 = 0; c8 < 8; ++c8) {
        const int co = coh * 8 + c8;
        out[ob + c8 * POOL3] = fmaf(acc[c8], ab[co], ab[16 + co]);
    }
}

extern "C" void kernel_launch(void* const* d_in, const int* in_sizes, int n_in,
                              void* d_out, int out_size, void* d_ws, size_t ws_size,
                              hipStream_t stream) {
    const float* x     = (const float*)d_in[0];
    const float* w     = (const float*)d_in[1];
    const float* gamma = (const float*)d_in[2];
    const float* beta  = (const float*)d_in[3];
    float* out = (float*)d_out;
    float* ws  = (float*)d_ws;

    mega_k<<<722, 256, 0, stream>>>(x, w, ws + WS_A3P, ws + WS_X3P,
                                    ws + WS_A2P, ws + WS_X2P,
                                    ws + WS_A1, ws + WS_X1, ws + WS_G);
    reduce_A3<<<62, 256, 0, stream>>>(ws + WS_A3P, ws + WS_X3P, ws + WS_A3R);
    finalize2<<<1, 256, 0, stream>>>(x, w, gamma, beta, ws, ws + WS_AB);
    pooled_norm<<<dim3(30, 32), 256, 0, stream>>>(x, ws + WS_G, ws + WS_AB, out);
}